// Round 12
// baseline (1495.089 us; speedup 1.0000x reference)
//
#include <hip/hip_runtime.h>
#include <hip/hip_bf16.h>

typedef unsigned short u16;
typedef __attribute__((ext_vector_type(8))) short short8;
typedef __attribute__((ext_vector_type(4))) float f32x4;

#define T_STEPS 256
#define BATCH   128
#define ISIZE   256
#define HSIZE   1024
#define GSIZE   4096
#define KCAT    1280

// workspace layout (bytes)
#define WCAT_OFF  0UL            // bf16 [4096][1280]  (w_hh | w_ih)
#define XBF_OFF   10485760UL     // bf16 [256][128][256]
#define ABUF_OFF  27262976UL     // bf16 2 x [128][1024]  (h only), ping-pong
#define BCOMB_OFF 27918336UL     // f32  [4096]  b_ih + b_hh
#define SUMS_OFF  27934720UL     // 12 doubles (KL partial sums)
#define FLAG_OFF  27934848UL     // 8 groups x 32 u32 agent flags
#define XCC_OFF   27935872UL     // 256 u32 xcc-id slots (mapping guard)

#define OUT_ELEMS ((size_t)T_STEPS * BATCH * HSIZE)
#define HN_OFF    (OUT_ELEMS)
#define CN_OFF    (OUT_ELEMS + (size_t)BATCH * HSIZE)
#define KL_OFF    (OUT_ELEMS + 2UL * BATCH * HSIZE)

static __device__ __forceinline__ u16 f2bf(float f) {
  union { __hip_bfloat16 h; u16 u; } cv;
  cv.h = __float2bfloat16(f);
  return cv.u;
}

static __device__ __forceinline__ f32x4 mfma16(short8 a, short8 b, f32x4 c) {
  return __builtin_amdgcn_mfma_f32_16x16x32_bf16(a, b, c, 0, 0, 0);
}

static __device__ __forceinline__ float sigm(float v) {
  return 1.0f / (1.0f + __expf(-v));
}
static __device__ __forceinline__ float tanh_(float v) {
  v = fminf(12.0f, fmaxf(-12.0f, v));
  float e = __expf(2.0f * v);
  return (e - 1.0f) / (e + 1.0f);
}

// ---------------------------------------------------------------- prep ----
static __device__ void block_reduce_atomic(const float* v, int n, double* dst) {
  __shared__ float red[6][4];
  float loc[6];
  for (int i = 0; i < n; ++i) loc[i] = v[i];
#pragma unroll
  for (int off = 32; off > 0; off >>= 1)
    for (int i = 0; i < n; ++i) loc[i] += __shfl_down(loc[i], off, 64);
  __syncthreads();
  const int wv = threadIdx.x >> 6, ln = threadIdx.x & 63;
  if (ln == 0)
    for (int i = 0; i < n; ++i) red[i][wv] = loc[i];
  __syncthreads();
  if (threadIdx.x == 0)
    for (int i = 0; i < n; ++i)
      atomicAdd(dst + i, (double)(red[i][0] + red[i][1] + red[i][2] + red[i][3]));
  __syncthreads();
}

__global__ __launch_bounds__(256) void prep_kernel(
    const float* __restrict__ x,
    const float* __restrict__ wih_mu, const float* __restrict__ wih_rho,
    const float* __restrict__ whh_mu, const float* __restrict__ whh_rho,
    const float* __restrict__ bih_mu, const float* __restrict__ bih_rho,
    const float* __restrict__ bhh_mu, const float* __restrict__ bhh_rho,
    const float* __restrict__ eih, const float* __restrict__ ehh,
    const float* __restrict__ ebi, const float* __restrict__ ebh,
    u16* __restrict__ wcat, u16* __restrict__ xbf,
    float* __restrict__ bcomb, double* __restrict__ sums)
{
  const unsigned stride = gridDim.x * blockDim.x;
  const unsigned tid0 = blockIdx.x * blockDim.x + threadIdx.x;
  float s[6];

  // ---- w_ih (tensor 0): [4096][256] -> wcat cols 1024..1279
  s[0] = s[1] = s[2] = 0.f;
  for (unsigned i = tid0; i < GSIZE * ISIZE; i += stride) {
    float mu = wih_mu[i], rho = wih_rho[i], ep = eih[i];
    float sg = log1pf(__expf(rho)) + 1e-5f;
    float w  = fmaf(ep, sg, mu);
    unsigned g = i >> 8, k = i & 255u;
    wcat[(size_t)g * KCAT + HSIZE + k] = f2bf(w);
    s[0] += ep * ep; s[1] += __logf(sg); s[2] += w * w;
  }
  block_reduce_atomic(s, 3, sums + 0);

  // ---- w_hh (tensor 1): [4096][1024] -> wcat cols 0..1023
  s[0] = s[1] = s[2] = 0.f;
  for (unsigned i = tid0; i < GSIZE * HSIZE; i += stride) {
    float mu = whh_mu[i], rho = whh_rho[i], ep = ehh[i];
    float sg = log1pf(__expf(rho)) + 1e-5f;
    float w  = fmaf(ep, sg, mu);
    unsigned g = i >> 10, k = i & 1023u;
    wcat[(size_t)g * KCAT + k] = f2bf(w);
    s[0] += ep * ep; s[1] += __logf(sg); s[2] += w * w;
  }
  block_reduce_atomic(s, 3, sums + 3);

  // ---- biases (tensors 2,3) + combined bias
  for (int i = 0; i < 6; ++i) s[i] = 0.f;
  for (unsigned i = tid0; i < GSIZE; i += stride) {
    float mu = bih_mu[i], rho = bih_rho[i], ep = ebi[i];
    float sg = log1pf(__expf(rho)) + 1e-5f;
    float w  = fmaf(ep, sg, mu);
    s[0] += ep * ep; s[1] += __logf(sg); s[2] += w * w;
    float mu2 = bhh_mu[i], rho2 = bhh_rho[i], ep2 = ebh[i];
    float sg2 = log1pf(__expf(rho2)) + 1e-5f;
    float w2  = fmaf(ep2, sg2, mu2);
    s[3] += ep2 * ep2; s[4] += __logf(sg2); s[5] += w2 * w2;
    bcomb[i] = w + w2;
  }
  block_reduce_atomic(s, 6, sums + 6);

  // ---- x -> bf16
  for (unsigned i = tid0; i < (unsigned)T_STEPS * BATCH * ISIZE; i += stride)
    xbf[i] = f2bf(x[i]);
}

// ---------------------------------------------------------- kl finalize ----
__global__ void kl_finalize(const double* __restrict__ sums, float* __restrict__ out_kl) {
  const double LOG2PI = 1.8378770664093453;
  const double Ns[4] = {1048576.0, 4194304.0, 4096.0, 4096.0};
  double kl = 0.0;
#pragma unroll
  for (int t = 0; t < 4; ++t) {
    double S1 = sums[t * 3 + 0], S2 = sums[t * 3 + 1], S3 = sums[t * 3 + 2];
    double N = Ns[t];
    double log_post = -0.5 * S1 - S2 - 0.5 * N * LOG2PI;
    double mix1 = -0.5 * S3 - 0.5 * N * LOG2PI + log(0.75);
    double mix2 = -0.5 * S3 * 1.0e6 - N * log(1.0e-3) - 0.5 * N * LOG2PI + log(0.25);
    double mx = fmax(mix1, mix2), mn = fmin(mix1, mix2);
    double log_prior = mx + log1p(exp(mn - mx));
    kl += log_post - log_prior;
  }
  *out_kl = (float)kl;
}

// ---------------------------------------------- coherence-aware helpers ----
static __device__ __forceinline__ short8 loadA16(const u16* p) {
  short8 r;
  asm volatile("global_load_dwordx4 %0, %1, off sc0" : "=&v"(r) : "v"(p));
  return r;
}

// publish: agent-scope atomic store -- the ONLY proven fast-visibility
// signaling primitive on this chip (R8/R10 bisections: non-atomic flag
// stores are never observed by inv+load polls).
static __device__ __forceinline__ void publish_flag(unsigned* p, unsigned v, bool strong) {
  if (strong)
    __hip_atomic_store(p, v, __ATOMIC_RELEASE, __HIP_MEMORY_SCOPE_AGENT);
  else
    __hip_atomic_store(p, v, __ATOMIC_RELAXED, __HIP_MEMORY_SCOPE_AGENT);
}

// strong-mode poll (R6-proven): agent atomic loads + one acquire fence.
static __device__ __forceinline__ void wait_group_strong(const unsigned* f, unsigned target) {
  const int lane = threadIdx.x & 63;
  unsigned v;
  do {
    v = (lane < 32) ? __hip_atomic_load(f + lane, __ATOMIC_RELAXED, __HIP_MEMORY_SCOPE_AGENT)
                    : target;
  } while (!__all((int)(v >= target)));
  __builtin_amdgcn_fence(__ATOMIC_ACQUIRE, "agent");
}

// ---------------------------------------------------------------- lstm ----
// grid = 256 blocks (8 bm-groups x 32 bj), block = 512 threads (8 waves).
// Dataflow doorbells, R11 fixed: wave 7 (x-only) polls the 32 agent flags
// FIRST (its x-MFMA happens after the pass, off the chain); wave 6 co-polls
// with an s_sleep phase offset (2x effective poll rate on the LLC flags)
// until its own 2 slices are ready. Doorbell mirrors use LDS atomicMax
// (monotonic -> no lost-update, no stuck-low deadlock). Waves 0..5 spin on
// their 5-slice LDS window. Strong path (impure XCD mapping) = R6 exactly.
__global__ __launch_bounds__(512, 2) void lstm_kernel(
    const u16* __restrict__ wcat, const u16* __restrict__ xbf,
    u16* __restrict__ abuf, const float* __restrict__ bcomb,
    float* __restrict__ out, unsigned* __restrict__ flags,
    unsigned* __restrict__ xccs)
{
  __shared__ float gates_p[8][16][128];   // 64 KB partial-gate exchange
  __shared__ volatile unsigned fsh[32];   // LDS doorbells (monotonic via ds_max)

  const int tid  = threadIdx.x;
  const int wv   = tid >> 6;          // 0..7 K-slice wave
  const int lane = tid & 63;
  const int col  = lane & 15;
  const int ksub = lane >> 4;
  const int bm   = blockIdx.x & 7;    // XCD-local group id
  const int bj   = blockIdx.x >> 3;   // member within group
  const int j0   = bj << 5;           // hidden-col tile base (32 wide)
  const int b0   = bm << 4;           // batch-row tile base (16 rows)
  const int wsw  = (ksub & 1) << 4;   // LDS write XOR swizzle (bank fix)
  const int sbase = wv * 5;           // first k-slice of this wave
  const int nf = (sbase >= 32) ? 0 : ((32 - sbase) < 5 ? (32 - sbase) : 5); // h producers

  unsigned* gflags = flags + bm * 32;

  if (tid < 32) fsh[tid] = 0u;        // zero doorbells before any spin

  // ---- one-time XCD-mapping guard ----
  unsigned xcc;
  asm volatile("s_getreg_b32 %0, hwreg(20, 0, 32)" : "=s"(xcc));  // HW_REG_XCC_ID
  xcc = (xcc & 15u) + 1u;
  if (tid == 0)
    __hip_atomic_store(xccs + blockIdx.x, xcc, __ATOMIC_RELAXED, __HIP_MEMORY_SCOPE_AGENT);
  bool strong;
  {
    unsigned mine = 0, head = 0;
    int filled;
    do {
      filled = 1;
      if (tid < 256) {
        mine = __hip_atomic_load(xccs + tid, __ATOMIC_RELAXED, __HIP_MEMORY_SCOPE_AGENT);
        head = __hip_atomic_load(xccs + (tid & 7), __ATOMIC_RELAXED, __HIP_MEMORY_SCOPE_AGENT);
        filled = (mine != 0u) && (head != 0u);
      }
    } while (!__syncthreads_and(filled));
    int match = (tid < 256) ? (mine == head) : 1;
    strong = !__syncthreads_and(match);   // global decision; also fences fsh init
  }

  // ---- pin W fragments in registers: wfrag[i][n], kk = wv*5 + i
  short8 wfrag[5][8];
#pragma unroll
  for (int i = 0; i < 5; ++i) {
    const int kk = sbase + i;
#pragma unroll
    for (int n = 0; n < 8; ++n) {
      const int rowg = ((n >> 1) << 10) + j0 + ((n & 1) << 4) + col;
      wfrag[i][n] = *(const short8*)(wcat + (size_t)rowg * KCAT + (kk << 5) + (ksub << 3));
    }
  }
  // Opaque touch: asm results cannot be rematerialized -> W stays resident
#pragma unroll
  for (int i = 0; i < 5; ++i)
#pragma unroll
    for (int n = 0; n < 8; ++n)
      asm volatile("" : "+v"(wfrag[i][n]));

  // cell ownership: 1 cell / thread; bias applied in cell phase
  const int bl = tid >> 5;   // 0..15 batch row
  const int jj = tid & 31;   // 0..31 hidden col
  const int rsw = ((bl >> 2) & 1) << 4;  // read-side swizzle (writer's ksub&1)
  float cbias[4];
#pragma unroll
  for (int g = 0; g < 4; ++g) cbias[g] = bcomb[(g << 10) + j0 + jj];
  float creg = 0.f;

  // prologue: h(0)=0 from host-side memset; publish readiness.
  if (tid == 0) publish_flag(gflags + bj, 1u, strong);

  for (int t = 0; t < T_STEPS; ++t) {
    const u16* curA = abuf + (size_t)(t & 1) * (BATCH * HSIZE);
    u16*       nxtA = abuf + (size_t)((t & 1) ^ 1) * (BATCH * HSIZE);
    const unsigned target = (unsigned)(t + 1);

    // x-slice loads issued EARLY (immutable, no flag needed)
    short8 av[5];
    const u16* xbase = xbf + ((size_t)t * BATCH + b0 + col) * ISIZE + (ksub << 3);
#pragma unroll
    for (int i = 0; i < 5; ++i) {
      const int kk = sbase + i;
      if (kk >= 32) av[i] = loadA16(xbase + ((kk - 32) << 5));
    }

    if (strong) {
      // R6-exact path: wave 0 polls, block joins, acquire fence done in poll
      if (wv == 0) wait_group_strong(gflags, target);
      __syncthreads();
    } else if (wv == 7) {
      // PURE POLLER FIRST (R11 flaw fixed): mirror flags into LDS doorbells
      // until every producer reached target. x-MFMA deferred to after pass.
      unsigned v;
      do {
        v = target;
        if (lane < 32) {
          v = __hip_atomic_load(gflags + lane, __ATOMIC_RELAXED, __HIP_MEMORY_SCOPE_AGENT);
          atomicMax((unsigned*)&fsh[lane], v);   // monotonic mirror
        }
      } while (!__all((int)(v >= target)));
      // x-only MFMA, off the critical path now
      asm volatile("s_waitcnt vmcnt(0)" ::: "memory");
      __builtin_amdgcn_sched_barrier(0);
      f32x4 acc7[8] = {};
#pragma unroll
      for (int i = 0; i < 5; ++i)
#pragma unroll
        for (int n = 0; n < 8; ++n)
          acc7[n] = mfma16(av[i], wfrag[i][n], acc7[n]);
#pragma unroll
      for (int n = 0; n < 8; ++n)
#pragma unroll
        for (int v2 = 0; v2 < 4; ++v2)
          gates_p[7][ksub * 4 + v2][((n << 4) + col) ^ wsw] = acc7[n][v2];
      goto exchange;
    } else if (wv == 6) {
      // CO-POLLER, phase-offset by ~770cy: doubles effective poll rate on
      // the LLC flags; exits as soon as ITS 2 slices (30,31) are ready.
      __builtin_amdgcn_s_sleep(12);
      bool mine;
      do {
        unsigned v = target;
        if (lane < 32) {
          v = __hip_atomic_load(gflags + lane, __ATOMIC_RELAXED, __HIP_MEMORY_SCOPE_AGENT);
          atomicMax((unsigned*)&fsh[lane], v);   // monotonic mirror
        }
        mine = (fsh[30] >= target) && (fsh[31] >= target);
      } while (!__all((int)mine));
    } else {
      // waves 0..5: spin on my 5-producer LDS doorbells (no LLC traffic)
      bool ok;
      do {
        ok = true;
#pragma unroll
        for (int i = 0; i < 5; ++i)
          if (i < nf) ok &= (fsh[sbase + i] >= target);
      } while (!ok);
    }

    // h-slice loads: CU-L1 inv first (fresh h dirty in same-XCD L2)
    if (!strong) asm volatile("buffer_inv" ::: "memory");
    {
      const u16* hbase = curA + (size_t)(b0 + col) * HSIZE + (ksub << 3);
#pragma unroll
      for (int i = 0; i < 5; ++i) {
        const int kk = sbase + i;
        if (kk < 32) av[i] = loadA16(hbase + (kk << 5));
      }
    }
    asm volatile("s_waitcnt vmcnt(0)" ::: "memory");
    __builtin_amdgcn_sched_barrier(0);

    {
      f32x4 acc[8] = {};
#pragma unroll
      for (int i = 0; i < 5; ++i)
#pragma unroll
        for (int n = 0; n < 8; ++n)
          acc[n] = mfma16(av[i], wfrag[i][n], acc[n]);

      // store partial gates (col XOR-swizzled by (ksub&1)<<4)
#pragma unroll
      for (int n = 0; n < 8; ++n)
#pragma unroll
        for (int v = 0; v < 4; ++v)
          gates_p[wv][ksub * 4 + v][((n << 4) + col) ^ wsw] = acc[n][v];
    }

exchange:
    __syncthreads();   // exchange barrier: all waves' partials in LDS

    // cell update: sum 8 K-partials per gate, add bias
    float h, cn;
    {
      float gi = 0.f, gf = 0.f, gg = 0.f, go = 0.f;
#pragma unroll
      for (int w = 0; w < 8; ++w) {
        gi += gates_p[w][bl][jj ^ rsw];
        gf += gates_p[w][bl][(32 + jj) ^ rsw];
        gg += gates_p[w][bl][(64 + jj) ^ rsw];
        go += gates_p[w][bl][(96 + jj) ^ rsw];
      }
      gi += cbias[0]; gf += cbias[1]; gg += cbias[2]; go += cbias[3];
      float ig = sigm(gi), fg = sigm(gf), og = sigm(go);
      cn = fg * creg + ig * tanh_(gg);
      creg = cn;
      h = og * tanh_(cn);
      // h-store ONLY before the drain sync (keeps publish path minimal)
      nxtA[(size_t)(b0 + bl) * HSIZE + (j0 + jj)] = f2bf(h);
    }
    __syncthreads();   // drain: all h stores committed in L2 (compiler vmcnt)

    if (tid == 0 && t + 1 < T_STEPS)
      publish_flag(gflags + bj, (unsigned)(t + 2), strong);

    // deferred (off the serial chain): out stores overlap next step's wait
    {
      size_t hidx = (size_t)(b0 + bl) * HSIZE + (size_t)(j0 + jj);
      out[(size_t)t * (BATCH * HSIZE) + hidx] = h;
      if (t == T_STEPS - 1) {
        out[HN_OFF + hidx] = h;
        out[CN_OFF + hidx] = cn;
      }
    }
  }
}

// -------------------------------------------------------------- launch ----
extern "C" void kernel_launch(void* const* d_in, const int* in_sizes, int n_in,
                              void* d_out, int out_size, void* d_ws, size_t ws_size,
                              hipStream_t stream) {
  (void)in_sizes; (void)n_in; (void)out_size; (void)ws_size;
  const float* x       = (const float*)d_in[0];
  const float* wih_mu  = (const float*)d_in[1];
  const float* wih_rho = (const float*)d_in[2];
  const float* whh_mu  = (const float*)d_in[3];
  const float* whh_rho = (const float*)d_in[4];
  const float* bih_mu  = (const float*)d_in[5];
  const float* bih_rho = (const float*)d_in[6];
  const float* bhh_mu  = (const float*)d_in[7];
  const float* bhh_rho = (const float*)d_in[8];
  const float* eih     = (const float*)d_in[9];
  const float* ehh     = (const float*)d_in[10];
  const float* ebi     = (const float*)d_in[11];
  const float* ebh     = (const float*)d_in[12];

  float* out = (float*)d_out;
  char* ws = (char*)d_ws;
  u16* wcat    = (u16*)(ws + WCAT_OFF);
  u16* xbf     = (u16*)(ws + XBF_OFF);
  u16* abuf    = (u16*)(ws + ABUF_OFF);
  float* bcomb = (float*)(ws + BCOMB_OFF);
  double* sums = (double*)(ws + SUMS_OFF);
  unsigned* flags = (unsigned*)(ws + FLAG_OFF);
  unsigned* xccs  = (unsigned*)(ws + XCC_OFF);

  hipMemsetAsync(ws + SUMS_OFF, 0, 2176, stream);                   // sums + flags + xcc slots
  hipMemsetAsync(ws + ABUF_OFF, 0, 2UL * BATCH * HSIZE * 2, stream);// h ping-pong

  prep_kernel<<<512, 256, 0, stream>>>(x, wih_mu, wih_rho, whh_mu, whh_rho,
      bih_mu, bih_rho, bhh_mu, bhh_rho, eih, ehh, ebi, ebh, wcat, xbf, bcomb, sums);
  kl_finalize<<<1, 1, 0, stream>>>(sums, out + KL_OFF);
  lstm_kernel<<<256, 512, 0, stream>>>(wcat, xbf, abuf, bcomb, out, flags, xccs);
}

// Round 13
// 928.267 us; speedup vs baseline: 1.6106x; 1.6106x over previous
//
#include <hip/hip_runtime.h>
#include <hip/hip_bf16.h>

typedef unsigned short u16;
typedef __attribute__((ext_vector_type(8))) short short8;
typedef __attribute__((ext_vector_type(4))) float f32x4;

#define T_STEPS 256
#define BATCH   128
#define ISIZE   256
#define HSIZE   1024
#define GSIZE   4096
#define KCAT    1280

// workspace layout (bytes)
#define WCAT_OFF  0UL            // bf16 [4096][1280]  (w_hh | w_ih)
#define XBF_OFF   10485760UL     // bf16 [256][128][256]
#define ABUF_OFF  27262976UL     // bf16 2 x [128][1024]  (h only), ping-pong
#define BCOMB_OFF 27918336UL     // f32  [4096]  b_ih + b_hh
#define SUMS_OFF  27934720UL     // 12 doubles (KL partial sums)
#define FLAG_OFF  27934848UL     // 8 groups x 32 flags, EACH PADDED TO 64B (16 KB)
#define XCC_OFF   27951232UL     // 256 u32 xcc-id slots (mapping guard)

#define OUT_ELEMS ((size_t)T_STEPS * BATCH * HSIZE)
#define HN_OFF    (OUT_ELEMS)
#define CN_OFF    (OUT_ELEMS + (size_t)BATCH * HSIZE)
#define KL_OFF    (OUT_ELEMS + 2UL * BATCH * HSIZE)

static __device__ __forceinline__ u16 f2bf(float f) {
  union { __hip_bfloat16 h; u16 u; } cv;
  cv.h = __float2bfloat16(f);
  return cv.u;
}

static __device__ __forceinline__ f32x4 mfma16(short8 a, short8 b, f32x4 c) {
  return __builtin_amdgcn_mfma_f32_16x16x32_bf16(a, b, c, 0, 0, 0);
}

static __device__ __forceinline__ float sigm(float v) {
  return 1.0f / (1.0f + __expf(-v));
}
static __device__ __forceinline__ float tanh_(float v) {
  v = fminf(12.0f, fmaxf(-12.0f, v));
  float e = __expf(2.0f * v);
  return (e - 1.0f) / (e + 1.0f);
}

// ---------------------------------------------------------------- prep ----
static __device__ void block_reduce_atomic(const float* v, int n, double* dst) {
  __shared__ float red[6][4];
  float loc[6];
  for (int i = 0; i < n; ++i) loc[i] = v[i];
#pragma unroll
  for (int off = 32; off > 0; off >>= 1)
    for (int i = 0; i < n; ++i) loc[i] += __shfl_down(loc[i], off, 64);
  __syncthreads();
  const int wv = threadIdx.x >> 6, ln = threadIdx.x & 63;
  if (ln == 0)
    for (int i = 0; i < n; ++i) red[i][wv] = loc[i];
  __syncthreads();
  if (threadIdx.x == 0)
    for (int i = 0; i < n; ++i)
      atomicAdd(dst + i, (double)(red[i][0] + red[i][1] + red[i][2] + red[i][3]));
  __syncthreads();
}

__global__ __launch_bounds__(256) void prep_kernel(
    const float* __restrict__ x,
    const float* __restrict__ wih_mu, const float* __restrict__ wih_rho,
    const float* __restrict__ whh_mu, const float* __restrict__ whh_rho,
    const float* __restrict__ bih_mu, const float* __restrict__ bih_rho,
    const float* __restrict__ bhh_mu, const float* __restrict__ bhh_rho,
    const float* __restrict__ eih, const float* __restrict__ ehh,
    const float* __restrict__ ebi, const float* __restrict__ ebh,
    u16* __restrict__ wcat, u16* __restrict__ xbf,
    float* __restrict__ bcomb, double* __restrict__ sums)
{
  const unsigned stride = gridDim.x * blockDim.x;
  const unsigned tid0 = blockIdx.x * blockDim.x + threadIdx.x;
  float s[6];

  // ---- w_ih (tensor 0): [4096][256] -> wcat cols 1024..1279
  s[0] = s[1] = s[2] = 0.f;
  for (unsigned i = tid0; i < GSIZE * ISIZE; i += stride) {
    float mu = wih_mu[i], rho = wih_rho[i], ep = eih[i];
    float sg = log1pf(__expf(rho)) + 1e-5f;
    float w  = fmaf(ep, sg, mu);
    unsigned g = i >> 8, k = i & 255u;
    wcat[(size_t)g * KCAT + HSIZE + k] = f2bf(w);
    s[0] += ep * ep; s[1] += __logf(sg); s[2] += w * w;
  }
  block_reduce_atomic(s, 3, sums + 0);

  // ---- w_hh (tensor 1): [4096][1024] -> wcat cols 0..1023
  s[0] = s[1] = s[2] = 0.f;
  for (unsigned i = tid0; i < GSIZE * HSIZE; i += stride) {
    float mu = whh_mu[i], rho = whh_rho[i], ep = ehh[i];
    float sg = log1pf(__expf(rho)) + 1e-5f;
    float w  = fmaf(ep, sg, mu);
    unsigned g = i >> 10, k = i & 1023u;
    wcat[(size_t)g * KCAT + k] = f2bf(w);
    s[0] += ep * ep; s[1] += __logf(sg); s[2] += w * w;
  }
  block_reduce_atomic(s, 3, sums + 3);

  // ---- biases (tensors 2,3) + combined bias
  for (int i = 0; i < 6; ++i) s[i] = 0.f;
  for (unsigned i = tid0; i < GSIZE; i += stride) {
    float mu = bih_mu[i], rho = bih_rho[i], ep = ebi[i];
    float sg = log1pf(__expf(rho)) + 1e-5f;
    float w  = fmaf(ep, sg, mu);
    s[0] += ep * ep; s[1] += __logf(sg); s[2] += w * w;
    float mu2 = bhh_mu[i], rho2 = bhh_rho[i], ep2 = ebh[i];
    float sg2 = log1pf(__expf(rho2)) + 1e-5f;
    float w2  = fmaf(ep2, sg2, mu2);
    s[3] += ep2 * ep2; s[4] += __logf(sg2); s[5] += w2 * w2;
    bcomb[i] = w + w2;
  }
  block_reduce_atomic(s, 6, sums + 6);

  // ---- x -> bf16
  for (unsigned i = tid0; i < (unsigned)T_STEPS * BATCH * ISIZE; i += stride)
    xbf[i] = f2bf(x[i]);
}

// ---------------------------------------------------------- kl finalize ----
__global__ void kl_finalize(const double* __restrict__ sums, float* __restrict__ out_kl) {
  const double LOG2PI = 1.8378770664093453;
  const double Ns[4] = {1048576.0, 4194304.0, 4096.0, 4096.0};
  double kl = 0.0;
#pragma unroll
  for (int t = 0; t < 4; ++t) {
    double S1 = sums[t * 3 + 0], S2 = sums[t * 3 + 1], S3 = sums[t * 3 + 2];
    double N = Ns[t];
    double log_post = -0.5 * S1 - S2 - 0.5 * N * LOG2PI;
    double mix1 = -0.5 * S3 - 0.5 * N * LOG2PI + log(0.75);
    double mix2 = -0.5 * S3 * 1.0e6 - N * log(1.0e-3) - 0.5 * N * LOG2PI + log(0.25);
    double mx = fmax(mix1, mix2), mn = fmin(mix1, mix2);
    double log_prior = mx + log1p(exp(mn - mx));
    kl += log_post - log_prior;
  }
  *out_kl = (float)kl;
}

// ---------------------------------------------- coherence-aware helpers ----
static __device__ __forceinline__ short8 loadA16(const u16* p) {
  short8 r;
  asm volatile("global_load_dwordx4 %0, %1, off sc0" : "=&v"(r) : "v"(p));
  return r;
}

// publish: agent-scope atomic store -- the ONLY proven fast-visibility
// signaling primitive (R8/R10: non-atomic flag stores are never observed
// by inv+load polls). Flag now owns a full 64B line: the publish store no
// longer queues behind other flags' poll reads on a shared line.
static __device__ __forceinline__ void publish_flag(unsigned* p, unsigned v, bool strong) {
  if (strong)
    __hip_atomic_store(p, v, __ATOMIC_RELEASE, __HIP_MEMORY_SCOPE_AGENT);
  else
    __hip_atomic_store(p, v, __ATOMIC_RELAXED, __HIP_MEMORY_SCOPE_AGENT);
}

// single-wave poll of the group's 32 PADDED flags: lane l reads flag l at
// stride 16 u32 (64B) -> 32 DISTINCT LLC lines per poll round instead of 2
// shared ones. Per-line concurrency drops ~16x; publish visibility is no
// longer delayed by poll-read queues. Proven agent relaxed atomic loads.
static __device__ __forceinline__ void wait_group(const unsigned* f, unsigned target, bool strong) {
  const int lane = threadIdx.x & 63;
  unsigned v;
  do {
    v = (lane < 32) ? __hip_atomic_load(f + (lane << 4), __ATOMIC_RELAXED, __HIP_MEMORY_SCOPE_AGENT)
                    : target;
  } while (!__all((int)(v >= target)));
  if (strong)
    __builtin_amdgcn_fence(__ATOMIC_ACQUIRE, "agent");
}

// ---------------------------------------------------------------- lstm ----
// grid = 256 blocks (8 bm-groups x 32 bj), block = 512 threads (8 waves).
// R6 champion structure EXACTLY (999us total) with ONE change under test:
// each publish flag is padded to its own 64-B LLC line (stride 16 u32).
// Theory: the residual ~2.5us/step over the chain model is LLC line
// contention -- 32 blocks x 32-lane polls hammering the 2 cache lines that
// held all 32 packed flags, which also queued the producers' publish
// stores. Padding spreads polls over 32 lines and isolates each publisher.
// XCC_ID guard falls back to agent release/acquire on impure mappings.
__global__ __launch_bounds__(512, 2) void lstm_kernel(
    const u16* __restrict__ wcat, const u16* __restrict__ xbf,
    u16* __restrict__ abuf, const float* __restrict__ bcomb,
    float* __restrict__ out, unsigned* __restrict__ flags,
    unsigned* __restrict__ xccs)
{
  __shared__ float gates_p[8][16][128];   // 64 KB partial-gate exchange

  const int tid  = threadIdx.x;
  const int wv   = tid >> 6;          // 0..7 K-slice wave
  const int lane = tid & 63;
  const int col  = lane & 15;
  const int ksub = lane >> 4;
  const int bm   = blockIdx.x & 7;    // XCD-local group id
  const int bj   = blockIdx.x >> 3;   // member within group
  const int j0   = bj << 5;           // hidden-col tile base (32 wide)
  const int b0   = bm << 4;           // batch-row tile base (16 rows)
  const int wsw  = (ksub & 1) << 4;   // LDS write XOR swizzle (bank fix)
  const int sbase = wv * 5;           // first k-slice of this wave

  unsigned* gflags = flags + bm * 512;          // 32 flags x 16-u32 stride
  unsigned* myflag = gflags + (bj << 4);

  // ---- one-time XCD-mapping guard ----
  unsigned xcc;
  asm volatile("s_getreg_b32 %0, hwreg(20, 0, 32)" : "=s"(xcc));  // HW_REG_XCC_ID
  xcc = (xcc & 15u) + 1u;
  if (tid == 0)
    __hip_atomic_store(xccs + blockIdx.x, xcc, __ATOMIC_RELAXED, __HIP_MEMORY_SCOPE_AGENT);
  bool strong;
  {
    unsigned mine = 0, head = 0;
    int filled;
    do {
      filled = 1;
      if (tid < 256) {
        mine = __hip_atomic_load(xccs + tid, __ATOMIC_RELAXED, __HIP_MEMORY_SCOPE_AGENT);
        head = __hip_atomic_load(xccs + (tid & 7), __ATOMIC_RELAXED, __HIP_MEMORY_SCOPE_AGENT);
        filled = (mine != 0u) && (head != 0u);
      }
    } while (!__syncthreads_and(filled));
    int match = (tid < 256) ? (mine == head) : 1;
    strong = !__syncthreads_and(match);   // global decision: no fast/strong mixing
  }

  // ---- pin W fragments in registers: wfrag[i][n], kk = wv*5 + i
  short8 wfrag[5][8];
#pragma unroll
  for (int i = 0; i < 5; ++i) {
    const int kk = sbase + i;
#pragma unroll
    for (int n = 0; n < 8; ++n) {
      const int rowg = ((n >> 1) << 10) + j0 + ((n & 1) << 4) + col;
      wfrag[i][n] = *(const short8*)(wcat + (size_t)rowg * KCAT + (kk << 5) + (ksub << 3));
    }
  }
  // Opaque touch: asm results cannot be rematerialized -> W stays resident
#pragma unroll
  for (int i = 0; i < 5; ++i)
#pragma unroll
    for (int n = 0; n < 8; ++n)
      asm volatile("" : "+v"(wfrag[i][n]));

  // cell ownership: 1 cell / thread; bias applied in cell phase
  const int bl = tid >> 5;   // 0..15 batch row
  const int jj = tid & 31;   // 0..31 hidden col
  const int rsw = ((bl >> 2) & 1) << 4;  // read-side swizzle (writer's ksub&1)
  float cbias[4];
#pragma unroll
  for (int g = 0; g < 4; ++g) cbias[g] = bcomb[(g << 10) + j0 + jj];
  float creg = 0.f;

  // prologue: h(0)=0 from host-side memset; publish readiness.
  if (tid == 0) publish_flag(myflag, 1u, strong);

  for (int t = 0; t < T_STEPS; ++t) {
    const u16* curA = abuf + (size_t)(t & 1) * (BATCH * HSIZE);
    u16*       nxtA = abuf + (size_t)((t & 1) ^ 1) * (BATCH * HSIZE);

    // x-slice loads issued EARLY (immutable data, no flag needed): their
    // L3 latency hides under the flag wait + join.
    short8 av[5];
    const u16* xbase = xbf + ((size_t)t * BATCH + b0 + col) * ISIZE + (ksub << 3);
#pragma unroll
    for (int i = 0; i < 5; ++i) {
      const int kk = sbase + i;
      if (kk >= 32) av[i] = loadA16(xbase + ((kk - 32) << 5));
    }

    // wave 0 polls all 32 producer flags; other waves park at the barrier
    if (wv == 0) wait_group(gflags, (unsigned)(t + 1), strong);
    __syncthreads();

    // fast path: CU-local L1 invalidate; fresh h is dirty in same-XCD L2.
    if (!strong) asm volatile("buffer_inv" ::: "memory");

    // h-slice loads + explicit wait + fence against MFMA hoisting (rule #18)
    const u16* hbase = curA + (size_t)(b0 + col) * HSIZE + (ksub << 3);
#pragma unroll
    for (int i = 0; i < 5; ++i) {
      const int kk = sbase + i;
      if (kk < 32) av[i] = loadA16(hbase + (kk << 5));
    }
    asm volatile("s_waitcnt vmcnt(0)" ::: "memory");
    __builtin_amdgcn_sched_barrier(0);

    f32x4 acc[8] = {};
#pragma unroll
    for (int i = 0; i < 5; ++i)
#pragma unroll
      for (int n = 0; n < 8; ++n)
        acc[n] = mfma16(av[i], wfrag[i][n], acc[n]);

    // store partial gates (col XOR-swizzled by (ksub&1)<<4)
#pragma unroll
    for (int n = 0; n < 8; ++n)
#pragma unroll
      for (int v = 0; v < 4; ++v)
        gates_p[wv][ksub * 4 + v][((n << 4) + col) ^ wsw] = acc[n][v];
    __syncthreads();

    // cell update: sum 8 K-partials per gate, add bias here
    float h, cn;
    {
      float gi = 0.f, gf = 0.f, gg = 0.f, go = 0.f;
#pragma unroll
      for (int w = 0; w < 8; ++w) {
        gi += gates_p[w][bl][jj ^ rsw];
        gf += gates_p[w][bl][(32 + jj) ^ rsw];
        gg += gates_p[w][bl][(64 + jj) ^ rsw];
        go += gates_p[w][bl][(96 + jj) ^ rsw];
      }
      gi += cbias[0]; gf += cbias[1]; gg += cbias[2]; go += cbias[3];
      float ig = sigm(gi), fg = sigm(gf), og = sigm(go);
      cn = fg * creg + ig * tanh_(gg);
      creg = cn;
      h = og * tanh_(cn);
      // h-store ONLY before the drain sync (keeps publish path minimal)
      nxtA[(size_t)(b0 + bl) * HSIZE + (j0 + jj)] = f2bf(h);
    }
    __syncthreads();   // per-wave vmcnt drain: all h stores committed in L2

    if (tid == 0 && t + 1 < T_STEPS)
      publish_flag(myflag, (unsigned)(t + 2), strong);

    // deferred (off the serial chain): out stores overlap next step's wait
    {
      size_t hidx = (size_t)(b0 + bl) * HSIZE + (size_t)(j0 + jj);
      out[(size_t)t * (BATCH * HSIZE) + hidx] = h;
      if (t == T_STEPS - 1) {
        out[HN_OFF + hidx] = h;
        out[CN_OFF + hidx] = cn;
      }
    }
  }
}

// -------------------------------------------------------------- launch ----
extern "C" void kernel_launch(void* const* d_in, const int* in_sizes, int n_in,
                              void* d_out, int out_size, void* d_ws, size_t ws_size,
                              hipStream_t stream) {
  (void)in_sizes; (void)n_in; (void)out_size; (void)ws_size;
  const float* x       = (const float*)d_in[0];
  const float* wih_mu  = (const float*)d_in[1];
  const float* wih_rho = (const float*)d_in[2];
  const float* whh_mu  = (const float*)d_in[3];
  const float* whh_rho = (const float*)d_in[4];
  const float* bih_mu  = (const float*)d_in[5];
  const float* bih_rho = (const float*)d_in[6];
  const float* bhh_mu  = (const float*)d_in[7];
  const float* bhh_rho = (const float*)d_in[8];
  const float* eih     = (const float*)d_in[9];
  const float* ehh     = (const float*)d_in[10];
  const float* ebi     = (const float*)d_in[11];
  const float* ebh     = (const float*)d_in[12];

  float* out = (float*)d_out;
  char* ws = (char*)d_ws;
  u16* wcat    = (u16*)(ws + WCAT_OFF);
  u16* xbf     = (u16*)(ws + XBF_OFF);
  u16* abuf    = (u16*)(ws + ABUF_OFF);
  float* bcomb = (float*)(ws + BCOMB_OFF);
  double* sums = (double*)(ws + SUMS_OFF);
  unsigned* flags = (unsigned*)(ws + FLAG_OFF);
  unsigned* xccs  = (unsigned*)(ws + XCC_OFF);

  // zero sums + padded flags (16KB) + xcc slots (in-graph: reset each replay)
  hipMemsetAsync(ws + SUMS_OFF, 0, 17536, stream);
  hipMemsetAsync(ws + ABUF_OFF, 0, 2UL * BATCH * HSIZE * 2, stream); // h ping-pong

  prep_kernel<<<512, 256, 0, stream>>>(x, wih_mu, wih_rho, whh_mu, whh_rho,
      bih_mu, bih_rho, bhh_mu, bhh_rho, eih, ehh, ebi, ebh, wcat, xbf, bcomb, sums);
  kl_finalize<<<1, 1, 0, stream>>>(sums, out + KL_OFF);
  lstm_kernel<<<256, 512, 0, stream>>>(wcat, xbf, abuf, bcomb, out, flags, xccs);
}